// Round 1
// baseline (488.439 us; speedup 1.0000x reference)
//
#include <hip/hip_runtime.h>
#include <hip/hip_bf16.h>
#include <math.h>

#define BB 32
#define NN 4096
#define DD 512
#define HH 128      // D/4
#define R1 64       // rows per scores-block
#define KC 64       // K chunk
#define RP 128      // rows per pool-block
#define NC (NN/RP)  // 32 pool chunks
#define LN_EPS 1e-5f
#define MEPS 1e-8f

// ---------------- mask dtype sniffing (bool upload format is ambiguous) ----
__global__ void gmsp_detect(const unsigned int* __restrict__ m, int* __restrict__ flag) {
    if (threadIdx.x == 0 && blockIdx.x == 0) {
        int f = 0; // 0 = int32, 1 = uint8, 2 = float32
        for (int i = 0; i < 1024; ++i) {
            unsigned v = m[i];
            if (v == 0x3F800000u) { f = 2; break; }
            if (v > 1u)           { f = 1; break; }
        }
        *flag = f;
    }
}

__global__ __launch_bounds__(256) void gmsp_expand(const void* __restrict__ msrc,
                                                   const int* __restrict__ flag,
                                                   unsigned char* __restrict__ m8, int n) {
    int i = blockIdx.x * 256 + threadIdx.x;
    if (i >= n) return;
    int f = *flag;
    unsigned char v;
    if (f == 1)      v = (((const unsigned char*)msrc)[i] != 0);
    else if (f == 2) v = (((const float*)msrc)[i] != 0.0f);
    else             v = (((const int*)msrc)[i] != 0);
    m8[i] = v;
}

// ---------------- scores: tanh(x@W1 + b1)@w2 + b2, masked --------------------
__global__ __launch_bounds__(256) void gmsp_scores(
    const float* __restrict__ x, const float* __restrict__ w1,
    const float* __restrict__ b1, const float* __restrict__ w2,
    const float* __restrict__ b2, const unsigned char* __restrict__ m8,
    float* __restrict__ scores)
{
    __shared__ float As[R1][KC + 1];   // +1 pad: break bank aliasing on column reads
    __shared__ float Ws[KC][HH];
    int blk = blockIdx.x;
    int b = blk >> 6;                  // NN/R1 = 64
    int rowbase = (blk & 63) * R1;
    const float* xbase = x + ((size_t)b * NN + rowbase) * DD;
    int t = threadIdx.x;
    int tx = t & 31, ty = t >> 5;      // tx: 32 h-groups (4 h each), ty: 8 row-groups (8 rows each)

    float acc[8][4];
#pragma unroll
    for (int i = 0; i < 8; ++i)
#pragma unroll
        for (int j = 0; j < 4; ++j) acc[i][j] = 0.f;

    for (int kc = 0; kc < DD; kc += KC) {
        // stage A tile (64 rows x 64 k), scalar LDS writes from float4 global loads
        for (int idx = t; idx < R1 * (KC / 4); idx += 256) {
            int r = idx >> 4, kv = idx & 15;
            float4 v = *(const float4*)(xbase + (size_t)r * DD + kc + (kv << 2));
            As[r][kv * 4 + 0] = v.x; As[r][kv * 4 + 1] = v.y;
            As[r][kv * 4 + 2] = v.z; As[r][kv * 4 + 3] = v.w;
        }
        // stage W1 tile (64 k x 128 h) - contiguous
        const float4* wsrc = (const float4*)(w1 + (size_t)kc * HH);
        float4* wdst = (float4*)&Ws[0][0];
        for (int idx = t; idx < KC * HH / 4; idx += 256) wdst[idx] = wsrc[idx];
        __syncthreads();

#pragma unroll 8
        for (int k = 0; k < KC; ++k) {
            float4 wq = *(const float4*)&Ws[k][tx << 2];
#pragma unroll
            for (int i = 0; i < 8; ++i) {
                float a = As[(ty << 3) + i][k];
                acc[i][0] = fmaf(a, wq.x, acc[i][0]);
                acc[i][1] = fmaf(a, wq.y, acc[i][1]);
                acc[i][2] = fmaf(a, wq.z, acc[i][2]);
                acc[i][3] = fmaf(a, wq.w, acc[i][3]);
            }
        }
        __syncthreads();
    }

    float b1v[4], w2v[4];
#pragma unroll
    for (int j = 0; j < 4; ++j) { b1v[j] = b1[(tx << 2) + j]; w2v[j] = w2[(tx << 2) + j]; }
    float sb[8];
#pragma unroll
    for (int i = 0; i < 8; ++i) {
        float s = 0.f;
#pragma unroll
        for (int j = 0; j < 4; ++j) s = fmaf(tanhf(acc[i][j] + b1v[j]), w2v[j], s);
        sb[i] = s;
    }
    // butterfly across the 32 h-groups (masks <32 keep lanes within their 32-half)
#pragma unroll
    for (int m = 16; m > 0; m >>= 1)
#pragma unroll
        for (int i = 0; i < 8; ++i) sb[i] += __shfl_xor(sb[i], m);

    if (tx == 0) {
        float bias = b2[0];
#pragma unroll
        for (int i = 0; i < 8; ++i) {
            size_t idx = (size_t)b * NN + rowbase + (ty << 3) + i;
            scores[idx] = m8[idx] ? (sb[i] + bias) : -INFINITY;
        }
    }
}

// ---------------- per-batch softmax stats + valid count ---------------------
__global__ __launch_bounds__(256) void gmsp_stats(
    const float* __restrict__ scores, const unsigned char* __restrict__ m8,
    float* __restrict__ smax, float* __restrict__ ssum, float* __restrict__ scnt)
{
    __shared__ float red[256];
    int b = blockIdx.x, t = threadIdx.x;
    const float* sr = scores + (size_t)b * NN;
    const unsigned char* mb = m8 + (size_t)b * NN;
    float m = -INFINITY;
    for (int n = t; n < NN; n += 256) m = fmaxf(m, sr[n]);
    red[t] = m; __syncthreads();
    for (int s = 128; s > 0; s >>= 1) { if (t < s) red[t] = fmaxf(red[t], red[t + s]); __syncthreads(); }
    float M = red[0]; __syncthreads();

    float e = 0.f, c = 0.f;
    for (int n = t; n < NN; n += 256) { e += expf(sr[n] - M); c += (float)mb[n]; }
    red[t] = e; __syncthreads();
    for (int s = 128; s > 0; s >>= 1) { if (t < s) red[t] += red[t + s]; __syncthreads(); }
    float E = red[0]; __syncthreads();
    red[t] = c; __syncthreads();
    for (int s = 128; s > 0; s >>= 1) { if (t < s) red[t] += red[t + s]; __syncthreads(); }
    float C = red[0];
    if (t == 0) { smax[b] = M; ssum[b] = E; scnt[b] = C; }
}

// ---------------- pooling partials (2nd x pass) -----------------------------
__global__ __launch_bounds__(256) void gmsp_pool(
    const float* __restrict__ x, const float* __restrict__ scores,
    const unsigned char* __restrict__ m8, const float* __restrict__ smax,
    const float* __restrict__ ssum, float* __restrict__ attnp,
    float* __restrict__ sump, float* __restrict__ maxp)
{
    __shared__ float wrow[RP];
    __shared__ unsigned char mrow[RP];
    int chunk = blockIdx.x, b = blockIdx.y, t = threadIdx.x;
    size_t rowoff = (size_t)b * NN + (size_t)chunk * RP;
    if (t < RP) {
        wrow[t] = expf(scores[rowoff + t] - smax[b]) / ssum[b]; // 0 for masked (-inf)
        mrow[t] = m8[rowoff + t];
    }
    __syncthreads();
    int d0 = t << 1;
    const float* xb = x + rowoff * DD + d0;
    float2 a = {0.f, 0.f}, s = {0.f, 0.f}, mv = {-INFINITY, -INFINITY};
    for (int r = 0; r < RP; ++r) {
        float2 xv = *(const float2*)(xb + (size_t)r * DD);
        float w = wrow[r];
        a.x = fmaf(w, xv.x, a.x); a.y = fmaf(w, xv.y, a.y);
        if (mrow[r]) { // uniform branch across the wave
            s.x += xv.x; s.y += xv.y;
            mv.x = fmaxf(mv.x, xv.x); mv.y = fmaxf(mv.y, xv.y);
        }
    }
    size_t obase = ((size_t)b * NC + chunk) * DD + d0;
    *(float2*)(attnp + obase) = a;
    *(float2*)(sump + obase) = s;
    *(float2*)(maxp + obase) = mv;
}

// ---------------- tail: reduce + gate MLP + combine + out proj --------------
__device__ __forceinline__ float gmsp_block_sum(float v, float* red, int t) {
    __syncthreads();
    red[t] = v; __syncthreads();
    for (int s = 128; s > 0; s >>= 1) { if (t < s) red[t] += red[t + s]; __syncthreads(); }
    return red[0];
}

__global__ __launch_bounds__(256) void gmsp_tail(
    const float* __restrict__ attnp, const float* __restrict__ sump,
    const float* __restrict__ maxp, const float* __restrict__ scnt,
    const float* __restrict__ gate_w1, const float* __restrict__ gate_b1,
    const float* __restrict__ gln_g, const float* __restrict__ gln_b,
    const float* __restrict__ gate_w2, const float* __restrict__ gate_b2,
    const float* __restrict__ out_w, const float* __restrict__ out_b,
    const float* __restrict__ oln_g, const float* __restrict__ oln_b,
    float* __restrict__ out)
{
    __shared__ float comb[3 * DD];
    __shared__ float wvec[DD];
    __shared__ float red[256];
    int b = blockIdx.x, t = threadIdx.x;
    int d0 = t << 1;

    // reduce pool partials
    float2 a = {0.f, 0.f}, s = {0.f, 0.f}, mv = {-INFINITY, -INFINITY};
    for (int c = 0; c < NC; ++c) {
        size_t base = ((size_t)b * NC + c) * DD + d0;
        float2 av = *(const float2*)(attnp + base);
        float2 sv = *(const float2*)(sump + base);
        float2 xv = *(const float2*)(maxp + base);
        a.x += av.x; a.y += av.y;
        s.x += sv.x; s.y += sv.y;
        mv.x = fmaxf(mv.x, xv.x); mv.y = fmaxf(mv.y, xv.y);
    }
    float cnt = scnt[b]; cnt = fmaxf(cnt, MEPS);
    float2 mean = {s.x / cnt, s.y / cnt};
    if (isinf(mv.x)) mv.x = 0.f;
    if (isinf(mv.y)) mv.y = 0.f;
    comb[d0] = a.x;            comb[d0 + 1] = a.y;
    comb[DD + d0] = mv.x;      comb[DD + d0 + 1] = mv.y;
    comb[2 * DD + d0] = mean.x; comb[2 * DD + d0 + 1] = mean.y;
    __syncthreads();

    // gate linear 1: [1536] @ [1536,512]
    float2 g = {gate_b1[d0], gate_b1[d0 + 1]};
    for (int k = 0; k < 3 * DD; ++k) {
        float c = comb[k];
        float2 wv = *(const float2*)(gate_w1 + (size_t)k * DD + d0);
        g.x = fmaf(c, wv.x, g.x); g.y = fmaf(c, wv.y, g.y);
    }
    // LN
    float mg = gmsp_block_sum(g.x + g.y, red, t) * (1.f / DD);
    float vg = gmsp_block_sum(g.x * g.x + g.y * g.y, red, t) * (1.f / DD) - mg * mg;
    float inv = rsqrtf(vg + LN_EPS);
    float gx = (g.x - mg) * inv * gln_g[d0] + gln_b[d0];
    float gy = (g.y - mg) * inv * gln_g[d0 + 1] + gln_b[d0 + 1];
    // exact GELU
    gx = 0.5f * gx * (1.f + erff(gx * 0.70710678118654752f));
    gy = 0.5f * gy * (1.f + erff(gy * 0.70710678118654752f));

    // gate linear 2 -> 3 logits
    float p0 = gx * gate_w2[d0 * 3 + 0] + gy * gate_w2[(d0 + 1) * 3 + 0];
    float p1 = gx * gate_w2[d0 * 3 + 1] + gy * gate_w2[(d0 + 1) * 3 + 1];
    float p2 = gx * gate_w2[d0 * 3 + 2] + gy * gate_w2[(d0 + 1) * 3 + 2];
    float l0 = gmsp_block_sum(p0, red, t) + gate_b2[0];
    float l1 = gmsp_block_sum(p1, red, t) + gate_b2[1];
    float l2 = gmsp_block_sum(p2, red, t) + gate_b2[2];
    float mx = fmaxf(l0, fmaxf(l1, l2));
    float e0 = expf(l0 - mx), e1 = expf(l1 - mx), e2 = expf(l2 - mx);
    float ie = 1.f / (e0 + e1 + e2);
    float gw0 = e0 * ie, gw1 = e1 * ie, gw2 = e2 * ie;

    // weighted combine
    wvec[d0]     = a.x * gw0 + mv.x * gw1 + mean.x * gw2;
    wvec[d0 + 1] = a.y * gw0 + mv.y * gw1 + mean.y * gw2;
    __syncthreads();

    // out projection: [512] @ [512,512]
    float2 o = {out_b[d0], out_b[d0 + 1]};
    for (int d = 0; d < DD; ++d) {
        float wd = wvec[d];
        float2 ow = *(const float2*)(out_w + (size_t)d * DD + d0);
        o.x = fmaf(wd, ow.x, o.x); o.y = fmaf(wd, ow.y, o.y);
    }
    // final LN
    float mo = gmsp_block_sum(o.x + o.y, red, t) * (1.f / DD);
    float vo = gmsp_block_sum(o.x * o.x + o.y * o.y, red, t) * (1.f / DD) - mo * mo;
    float io = rsqrtf(vo + LN_EPS);
    float2 res;
    res.x = (o.x - mo) * io * oln_g[d0] + oln_b[d0];
    res.y = (o.y - mo) * io * oln_g[d0 + 1] + oln_b[d0 + 1];
    *(float2*)(out + (size_t)b * DD + d0) = res;
}

extern "C" void kernel_launch(void* const* d_in, const int* in_sizes, int n_in,
                              void* d_out, int out_size, void* d_ws, size_t ws_size,
                              hipStream_t stream) {
    const float* x        = (const float*)d_in[0];
    const void*  mask     = d_in[1];
    const float* attn_w1  = (const float*)d_in[2];
    const float* attn_b1  = (const float*)d_in[3];
    const float* attn_w2  = (const float*)d_in[4];
    const float* attn_b2  = (const float*)d_in[5];
    const float* gate_w1  = (const float*)d_in[6];
    const float* gate_b1  = (const float*)d_in[7];
    const float* gln_g    = (const float*)d_in[8];
    const float* gln_b    = (const float*)d_in[9];
    const float* gate_w2  = (const float*)d_in[10];
    const float* gate_b2  = (const float*)d_in[11];
    const float* out_w    = (const float*)d_in[12];
    const float* out_b    = (const float*)d_in[13];
    const float* oln_g    = (const float*)d_in[14];
    const float* oln_b    = (const float*)d_in[15];
    float* out = (float*)d_out;

    char* p = (char*)d_ws;
    int* flag = (int*)p;                      p += 256;
    unsigned char* m8 = (unsigned char*)p;    p += (size_t)BB * NN;       // 128 KB
    float* scores = (float*)p;                p += (size_t)BB * NN * 4;   // 512 KB
    float* smax = (float*)p;                  p += 512;
    float* ssum = (float*)p;                  p += 512;
    float* scnt = (float*)p;                  p += 512;
    float* attnp = (float*)p;                 p += (size_t)BB * NC * DD * 4; // 2 MB
    float* sump = (float*)p;                  p += (size_t)BB * NC * DD * 4; // 2 MB
    float* maxp = (float*)p;                  p += (size_t)BB * NC * DD * 4; // 2 MB

    gmsp_detect<<<1, 64, 0, stream>>>((const unsigned int*)mask, flag);
    gmsp_expand<<<(BB * NN) / 256, 256, 0, stream>>>(mask, flag, m8, BB * NN);
    gmsp_scores<<<BB * (NN / R1), 256, 0, stream>>>(x, attn_w1, attn_b1, attn_w2, attn_b2, m8, scores);
    gmsp_stats<<<BB, 256, 0, stream>>>(scores, m8, smax, ssum, scnt);
    gmsp_pool<<<dim3(NC, BB), 256, 0, stream>>>(x, scores, m8, smax, ssum, attnp, sump, maxp);
    gmsp_tail<<<BB, 256, 0, stream>>>(attnp, sump, maxp, scnt,
                                      gate_w1, gate_b1, gln_g, gln_b, gate_w2, gate_b2,
                                      out_w, out_b, oln_g, oln_b, out);
}

// Round 2
// 188.992 us; speedup vs baseline: 2.5844x; 2.5844x over previous
//
#include <hip/hip_runtime.h>
#include <hip/hip_bf16.h>
#include <math.h>

#define BB 32
#define NN 4096
#define DD 512
#define HH 128
#define MT 64            // rows per fused block
#define NCH (NN/MT)      // 64 chunks per batch
#define LN_EPS 1e-5f
#define MEPS 1e-8f

typedef __attribute__((ext_vector_type(8))) short bf16x8;
typedef __attribute__((ext_vector_type(4))) float f32x4;

__device__ __forceinline__ unsigned pk_bf16(float a, float b) {
    unsigned ua = __float_as_uint(a); ua = (ua + 0x7FFFu + ((ua >> 16) & 1u)) >> 16;
    unsigned ub = __float_as_uint(b); ub = (ub + 0x7FFFu + ((ub >> 16) & 1u)) >> 16;
    return ua | (ub << 16);
}
__device__ __forceinline__ unsigned short bf16_1(float a) {
    unsigned ua = __float_as_uint(a);
    return (unsigned short)((ua + 0x7FFFu + ((ua >> 16) & 1u)) >> 16);
}
__device__ __forceinline__ float bflo(unsigned u) { return __uint_as_float(u << 16); }
__device__ __forceinline__ float bfhi(unsigned u) { return __uint_as_float(u & 0xFFFF0000u); }

// ---------------- mask dtype sniff (parallel, no serial L2-latency chain) ---
__global__ __launch_bounds__(1024) void gmsp_detect(const unsigned* __restrict__ m,
                                                    int* __restrict__ flag) {
    __shared__ int f8s, f32s;
    if (threadIdx.x == 0) { f8s = 0; f32s = 0; }
    __syncthreads();
    unsigned v = m[threadIdx.x];
    if (v == 0x3F800000u) atomicOr(&f32s, 1);
    else if (v > 1u)      atomicOr(&f8s, 1);
    __syncthreads();
    if (threadIdx.x == 0) *flag = f32s ? 2 : (f8s ? 1 : 0);
}

__global__ __launch_bounds__(256) void gmsp_expand(const void* __restrict__ msrc,
                                                   const int* __restrict__ flag,
                                                   unsigned char* __restrict__ m8, int n) {
    int i = blockIdx.x * 256 + threadIdx.x;
    if (i >= n) return;
    int f = *flag;
    unsigned char v;
    if (f == 1)      v = (((const unsigned char*)msrc)[i] != 0);
    else if (f == 2) v = (((const float*)msrc)[i] != 0.0f);
    else             v = (((const int*)msrc)[i] != 0);
    m8[i] = v;
}

// ---------------- W1 -> bf16, transposed to [h][k] for B-fragment loads -----
__global__ __launch_bounds__(256) void gmsp_prep_w1(const float* __restrict__ w1,
                                                    unsigned short* __restrict__ w1t) {
    int idx = blockIdx.x * 256 + threadIdx.x;  // 65536 = 512*128
    int k = idx >> 7, h = idx & 127;
    w1t[h * DD + k] = bf16_1(w1[idx]);
}

// ---------------- fused: scores MFMA + chunk softmax + pooling (1 x-pass) ---
__global__ __launch_bounds__(256) void gmsp_fused(
    const float* __restrict__ x, const unsigned short* __restrict__ w1t,
    const float* __restrict__ b1, const float* __restrict__ w2,
    const float* __restrict__ b2, const unsigned char* __restrict__ m8,
    unsigned short* __restrict__ attnp, unsigned short* __restrict__ sump,
    unsigned short* __restrict__ maxp, float* __restrict__ mc_arr,
    float* __restrict__ sc_arr, float* __restrict__ cnt_arr)
{
    __shared__ char xs_raw[MT * 1024];     // bf16 [64][512], XOR-swizzled rows
    __shared__ float sred[4][MT];
    __shared__ float wrow[MT];
    __shared__ unsigned char mrow[MT];

    int t = threadIdx.x;
    int blk = blockIdx.x;
    int b = blk >> 6;
    int chunk = blk & 63;
    size_t rowoff = (size_t)b * NN + (size_t)chunk * MT;
    const float* xbase = x + rowoff * DD;

    // stage x tile: fp32 global -> bf16 LDS, swizzle byte ^= (row&7)<<4
#pragma unroll
    for (int it = 0; it < 16; ++it) {
        int idx = it * 256 + t;            // 4096 groups of 8 floats
        int r = idx >> 6, g = idx & 63;
        const float4* src = (const float4*)(xbase + (size_t)r * DD + g * 8);
        float4 v0 = src[0], v1 = src[1];
        uint4 w;
        w.x = pk_bf16(v0.x, v0.y); w.y = pk_bf16(v0.z, v0.w);
        w.z = pk_bf16(v1.x, v1.y); w.w = pk_bf16(v1.z, v1.w);
        int ofs = r * 1024 + ((g << 4) ^ ((r & 7) << 4));
        *(uint4*)(xs_raw + ofs) = w;
    }
    if (t < MT) mrow[t] = m8[rowoff + t];
    __syncthreads();

    // MFMA: scores pre-activation. Wave wid owns h-cols [wid*32, wid*32+32)
    int lane = t & 63, wid = t >> 6;
    int l15 = lane & 15, lq = lane >> 4;
    int hb = wid * 32;
    f32x4 acc[4][2];
#pragma unroll
    for (int mt = 0; mt < 4; ++mt)
#pragma unroll
        for (int nt = 0; nt < 2; ++nt) acc[mt][nt] = (f32x4)0.f;

    const char* w1c0 = (const char*)(w1t + (size_t)(hb + l15) * DD) + lq * 16;
    const char* w1c1 = (const char*)(w1t + (size_t)(hb + 16 + l15) * DD) + lq * 16;
#pragma unroll
    for (int s = 0; s < 16; ++s) {
        bf16x8 bf0 = *(const bf16x8*)(w1c0 + s * 64);
        bf16x8 bf1 = *(const bf16x8*)(w1c1 + s * 64);
        int kb = s * 64 + lq * 16;
#pragma unroll
        for (int mt = 0; mt < 4; ++mt) {
            int row = mt * 16 + l15;
            bf16x8 af = *(const bf16x8*)(xs_raw + row * 1024 + (kb ^ ((row & 7) << 4)));
            acc[mt][0] = __builtin_amdgcn_mfma_f32_16x16x32_bf16(af, bf0, acc[mt][0], 0, 0, 0);
            acc[mt][1] = __builtin_amdgcn_mfma_f32_16x16x32_bf16(af, bf1, acc[mt][1], 0, 0, 0);
        }
    }

    // tanh + dot(w2): per-lane partial over its 2 h-columns, then xor-reduce
    float sp[4][4];
#pragma unroll
    for (int mt = 0; mt < 4; ++mt)
#pragma unroll
        for (int r = 0; r < 4; ++r) sp[mt][r] = 0.f;
#pragma unroll
    for (int nt = 0; nt < 2; ++nt) {
        int h = hb + nt * 16 + l15;
        float b1v = b1[h], w2v = w2[h];
#pragma unroll
        for (int mt = 0; mt < 4; ++mt)
#pragma unroll
            for (int r = 0; r < 4; ++r)
                sp[mt][r] += tanhf(acc[mt][nt][r] + b1v) * w2v;
    }
#pragma unroll
    for (int msk = 1; msk <= 8; msk <<= 1)
#pragma unroll
        for (int mt = 0; mt < 4; ++mt)
#pragma unroll
            for (int r = 0; r < 4; ++r) sp[mt][r] += __shfl_xor(sp[mt][r], msk);
    if (l15 == 0) {
#pragma unroll
        for (int mt = 0; mt < 4; ++mt)
#pragma unroll
            for (int r = 0; r < 4; ++r) sred[wid][mt * 16 + lq * 4 + r] = sp[mt][r];
    }
    __syncthreads();

    // wave 0: finalize scores, chunk-local softmax stats (unnormalized)
    if (t < MT) {
        float sc = sred[0][t] + sred[1][t] + sred[2][t] + sred[3][t] + b2[0];
        bool valid = mrow[t] != 0;
        float score = valid ? sc : -INFINITY;
        float mx = score;
#pragma unroll
        for (int msk = 1; msk <= 32; msk <<= 1) mx = fmaxf(mx, __shfl_xor(mx, msk));
        float se = valid ? expf(score - mx) : 0.f;
        float ssum = se, cnt = valid ? 1.f : 0.f;
#pragma unroll
        for (int msk = 1; msk <= 32; msk <<= 1) {
            ssum += __shfl_xor(ssum, msk);
            cnt  += __shfl_xor(cnt, msk);
        }
        wrow[t] = se;
        if (t == 0) { mc_arr[blk] = mx; sc_arr[blk] = ssum; cnt_arr[blk] = cnt; }
    }
    __syncthreads();

    // pooling from LDS bf16 tile: thread t owns cols (2t, 2t+1)
    int d0 = t * 2;
    float ax = 0.f, ay = 0.f, sx = 0.f, sy = 0.f;
    float mxv = -INFINITY, myv = -INFINITY;
#pragma unroll 8
    for (int r = 0; r < MT; ++r) {
        unsigned v = *(const unsigned*)(xs_raw + r * 1024 + ((d0 * 2) ^ ((r & 7) << 4)));
        float xlo = bflo(v), xhi = bfhi(v);
        float w = wrow[r];
        ax = fmaf(w, xlo, ax); ay = fmaf(w, xhi, ay);
        if (mrow[r]) {                       // uniform across wave
            sx += xlo; sy += xhi;
            mxv = fmaxf(mxv, xlo); myv = fmaxf(myv, xhi);
        }
    }
    size_t obase = (size_t)blk * DD + d0;
    *(unsigned*)(attnp + obase) = pk_bf16(ax, ay);
    *(unsigned*)(sump + obase)  = pk_bf16(sx, sy);
    *(unsigned*)(maxp + obase)  = pk_bf16(mxv, myv);
}

// ---------------- tail: flash-combine chunks + gate MLP + out proj ----------
__device__ __forceinline__ float gmsp_block_sum(float v, float* red, int t) {
    __syncthreads();
    red[t] = v; __syncthreads();
    for (int s = 128; s > 0; s >>= 1) { if (t < s) red[t] += red[t + s]; __syncthreads(); }
    return red[0];
}

__global__ __launch_bounds__(256) void gmsp_tail(
    const unsigned short* __restrict__ attnp, const unsigned short* __restrict__ sump,
    const unsigned short* __restrict__ maxp, const float* __restrict__ mc_arr,
    const float* __restrict__ sc_arr, const float* __restrict__ cnt_arr,
    const float* __restrict__ gate_w1, const float* __restrict__ gate_b1,
    const float* __restrict__ gln_g, const float* __restrict__ gln_b,
    const float* __restrict__ gate_w2, const float* __restrict__ gate_b2,
    const float* __restrict__ out_w, const float* __restrict__ out_b,
    const float* __restrict__ oln_g, const float* __restrict__ oln_b,
    float* __restrict__ out)
{
    __shared__ float comb[3 * DD];
    __shared__ float wvec[DD];
    __shared__ float red[256];
    __shared__ float ef[NCH];
    __shared__ float invT_s, cnt_s;
    int b = blockIdx.x, t = threadIdx.x;

    if (t < NCH) {
        float mc = mc_arr[b * NCH + t];
        float M = mc;
#pragma unroll
        for (int msk = 1; msk <= 32; msk <<= 1) M = fmaxf(M, __shfl_xor(M, msk));
        float e = (mc == -INFINITY) ? 0.f : expf(mc - M);
        float tot = e * sc_arr[b * NCH + t];
        float cnt = cnt_arr[b * NCH + t];
#pragma unroll
        for (int msk = 1; msk <= 32; msk <<= 1) {
            tot += __shfl_xor(tot, msk);
            cnt += __shfl_xor(cnt, msk);
        }
        ef[t] = e;
        if (t == 0) { invT_s = tot > 0.f ? 1.f / tot : 0.f; cnt_s = fmaxf(cnt, MEPS); }
    }
    __syncthreads();

    int d0 = t * 2;
    float ax = 0.f, ay = 0.f, sx = 0.f, sy = 0.f;
    float mx = -INFINITY, my = -INFINITY;
    for (int c = 0; c < NCH; ++c) {
        size_t base = ((size_t)b * NCH + c) * DD + d0;
        unsigned av = *(const unsigned*)(attnp + base);
        unsigned sv = *(const unsigned*)(sump + base);
        unsigned xv = *(const unsigned*)(maxp + base);
        float e = ef[c];
        ax = fmaf(e, bflo(av), ax); ay = fmaf(e, bfhi(av), ay);
        sx += bflo(sv); sy += bfhi(sv);
        mx = fmaxf(mx, bflo(xv)); my = fmaxf(my, bfhi(xv));
    }
    float invT = invT_s;
    ax *= invT; ay *= invT;
    float icnt = 1.f / cnt_s;
    float meanx = sx * icnt, meany = sy * icnt;
    if (isinf(mx)) mx = 0.f;
    if (isinf(my)) my = 0.f;

    comb[d0] = ax;               comb[d0 + 1] = ay;
    comb[DD + d0] = mx;          comb[DD + d0 + 1] = my;
    comb[2 * DD + d0] = meanx;   comb[2 * DD + d0 + 1] = meany;
    __syncthreads();

    // gate linear 1: [1536] @ [1536,512]
    float2 g = {gate_b1[d0], gate_b1[d0 + 1]};
    for (int k = 0; k < 3 * DD; ++k) {
        float c = comb[k];
        float2 wv = *(const float2*)(gate_w1 + (size_t)k * DD + d0);
        g.x = fmaf(c, wv.x, g.x); g.y = fmaf(c, wv.y, g.y);
    }
    float mg = gmsp_block_sum(g.x + g.y, red, t) * (1.f / DD);
    float vg = gmsp_block_sum(g.x * g.x + g.y * g.y, red, t) * (1.f / DD) - mg * mg;
    float inv = rsqrtf(vg + LN_EPS);
    float gx = (g.x - mg) * inv * gln_g[d0] + gln_b[d0];
    float gy = (g.y - mg) * inv * gln_g[d0 + 1] + gln_b[d0 + 1];
    gx = 0.5f * gx * (1.f + erff(gx * 0.70710678118654752f));
    gy = 0.5f * gy * (1.f + erff(gy * 0.70710678118654752f));

    float p0 = gx * gate_w2[d0 * 3 + 0] + gy * gate_w2[(d0 + 1) * 3 + 0];
    float p1 = gx * gate_w2[d0 * 3 + 1] + gy * gate_w2[(d0 + 1) * 3 + 1];
    float p2 = gx * gate_w2[d0 * 3 + 2] + gy * gate_w2[(d0 + 1) * 3 + 2];
    float l0 = gmsp_block_sum(p0, red, t) + gate_b2[0];
    float l1 = gmsp_block_sum(p1, red, t) + gate_b2[1];
    float l2 = gmsp_block_sum(p2, red, t) + gate_b2[2];
    float mxl = fmaxf(l0, fmaxf(l1, l2));
    float e0 = expf(l0 - mxl), e1 = expf(l1 - mxl), e2 = expf(l2 - mxl);
    float ie = 1.f / (e0 + e1 + e2);
    float gw0 = e0 * ie, gw1 = e1 * ie, gw2 = e2 * ie;

    wvec[d0]     = ax * gw0 + mx * gw1 + meanx * gw2;
    wvec[d0 + 1] = ay * gw0 + my * gw1 + meany * gw2;
    __syncthreads();

    float2 o = {out_b[d0], out_b[d0 + 1]};
    for (int d = 0; d < DD; ++d) {
        float wd = wvec[d];
        float2 ow = *(const float2*)(out_w + (size_t)d * DD + d0);
        o.x = fmaf(wd, ow.x, o.x); o.y = fmaf(wd, ow.y, o.y);
    }
    float mo = gmsp_block_sum(o.x + o.y, red, t) * (1.f / DD);
    float vo = gmsp_block_sum(o.x * o.x + o.y * o.y, red, t) * (1.f / DD) - mo * mo;
    float io = rsqrtf(vo + LN_EPS);
    float2 res;
    res.x = (o.x - mo) * io * oln_g[d0] + oln_b[d0];
    res.y = (o.y - mo) * io * oln_g[d0 + 1] + oln_b[d0 + 1];
    *(float2*)(out + (size_t)b * DD + d0) = res;
}

extern "C" void kernel_launch(void* const* d_in, const int* in_sizes, int n_in,
                              void* d_out, int out_size, void* d_ws, size_t ws_size,
                              hipStream_t stream) {
    const float* x        = (const float*)d_in[0];
    const void*  mask     = d_in[1];
    const float* attn_w1  = (const float*)d_in[2];
    const float* attn_b1  = (const float*)d_in[3];
    const float* attn_w2  = (const float*)d_in[4];
    const float* attn_b2  = (const float*)d_in[5];
    const float* gate_w1  = (const float*)d_in[6];
    const float* gate_b1  = (const float*)d_in[7];
    const float* gln_g    = (const float*)d_in[8];
    const float* gln_b    = (const float*)d_in[9];
    const float* gate_w2  = (const float*)d_in[10];
    const float* gate_b2  = (const float*)d_in[11];
    const float* out_w    = (const float*)d_in[12];
    const float* out_b    = (const float*)d_in[13];
    const float* oln_g    = (const float*)d_in[14];
    const float* oln_b    = (const float*)d_in[15];
    float* out = (float*)d_out;

    char* p = (char*)d_ws;
    int* flag = (int*)p;                       p += 256;
    unsigned char* m8 = (unsigned char*)p;     p += (size_t)BB * NN;            // 128 KB
    unsigned short* w1t = (unsigned short*)p;  p += (size_t)DD * HH * 2;        // 128 KB
    float* mc_arr = (float*)p;                 p += (size_t)BB * NCH * 4;       // 8 KB
    float* sc_arr = (float*)p;                 p += (size_t)BB * NCH * 4;
    float* cnt_arr = (float*)p;                p += (size_t)BB * NCH * 4;
    unsigned short* attnp = (unsigned short*)p; p += (size_t)BB * NCH * DD * 2; // 2 MB
    unsigned short* sump = (unsigned short*)p;  p += (size_t)BB * NCH * DD * 2; // 2 MB
    unsigned short* maxp = (unsigned short*)p;  p += (size_t)BB * NCH * DD * 2; // 2 MB

    gmsp_detect<<<1, 1024, 0, stream>>>((const unsigned*)mask, flag);
    gmsp_expand<<<(BB * NN) / 256, 256, 0, stream>>>(mask, flag, m8, BB * NN);
    gmsp_prep_w1<<<DD * HH / 256, 256, 0, stream>>>(attn_w1, w1t);
    gmsp_fused<<<BB * NCH, 256, 0, stream>>>(x, w1t, attn_b1, attn_w2, attn_b2, m8,
                                             attnp, sump, maxp, mc_arr, sc_arr, cnt_arr);
    gmsp_tail<<<BB, 256, 0, stream>>>(attnp, sump, maxp, mc_arr, sc_arr, cnt_arr,
                                      gate_w1, gate_b1, gln_g, gln_b, gate_w2, gate_b2,
                                      out_w, out_b, oln_g, oln_b, out);
}